// Round 7
// baseline (465.578 us; speedup 1.0000x reference)
//
#include <hip/hip_runtime.h>

#define NCN 50000   // nodes per type (N_C == N_N)
#define NE  500000  // edges per type
#define DF  128     // feature dim

// Binning parameters
#define BSHIFT 9                 // 512 dst nodes per bucket
#define NBUCK 98                 // ceil(50000/512)
#define BK 128                   // padded bucket count
#define CAP 7168                 // records per bucket (expected ~5120, uniform)
#define CHUNK 4096               // edges per binA block

typedef __attribute__((ext_vector_type(8))) short mfrag;   // 8 bf16 (4 VGPRs)
typedef __attribute__((ext_vector_type(4))) float facc4;   // 4 fp32 acc

__device__ inline ushort f2bf(float x) {                   // fp32 -> bf16 RNE
    unsigned u = __float_as_uint(x);
    unsigned r = (u + 0x7FFFu + ((u >> 16) & 1u)) >> 16;
    return (ushort)r;
}
__device__ inline float bf2f(ushort h) { return __uint_as_float(((unsigned)h) << 16); }

// split-bf16 store, float4 per 32-lane row: H table at T, L at T + NCN*DF
__device__ inline void store_split4(ushort* __restrict__ T, int row, int lane4,
                                    float4 v) {
    ushort h0 = f2bf(v.x); ushort l0 = f2bf(v.x - bf2f(h0));
    ushort h1 = f2bf(v.y); ushort l1 = f2bf(v.y - bf2f(h1));
    ushort h2 = f2bf(v.z); ushort l2 = f2bf(v.z - bf2f(h2));
    ushort h3 = f2bf(v.w); ushort l3 = f2bf(v.w - bf2f(h3));
    uint2 hp = make_uint2((uint)h0 | ((uint)h1 << 16), (uint)h2 | ((uint)h3 << 16));
    uint2 lp = make_uint2((uint)l0 | ((uint)l1 << 16), (uint)l2 | ((uint)l3 << 16));
    *(uint2*)(T + (size_t)row * DF + lane4 * 4) = hp;
    *(uint2*)(T + (size_t)NCN * DF + (size_t)row * DF + lane4 * 4) = lp;
}

// ---------------------------------------------------------------------------
// Out-degree histograms for the two GraphConv src-norm tables (L2-resident).
// ---------------------------------------------------------------------------
__global__ __launch_bounds__(256) void hist2_k(
    const int* __restrict__ cc_src, const int* __restrict__ cn_src,
    int* __restrict__ cnt2)
{
    int i = blockIdx.x * 256 + threadIdx.x;
    if (i >= NE) return;
    atomicAdd(&cnt2[cc_src[i]], 1);
    atomicAdd(&cnt2[NCN + cn_src[i]], 1);
}

__global__ __launch_bounds__(256) void srcnorm_k(
    const int* __restrict__ cnt2, float* __restrict__ snorm2, int n2)
{
    int i = blockIdx.x * 256 + threadIdx.x;
    if (i >= n2) return;
    int c = cnt2[i]; if (c < 1) c = 1;
    snorm2[i] = rsqrtf((float)c);
}

// ---------------------------------------------------------------------------
// Phase A: block-local counting sort of CHUNK edges into NBUCK dst-buckets,
// flushed as contiguous runs. streams: 0=cc 1=cn 2=nn (dst-keyed, src payload)
// ---------------------------------------------------------------------------
__global__ __launch_bounds__(256) void binA_k(
    const int* __restrict__ cc_src, const int* __restrict__ cc_dst,
    const int* __restrict__ cn_src, const int* __restrict__ cn_dst,
    const int* __restrict__ nn_src, const int* __restrict__ nn_dst,
    uint2* __restrict__ R, int* __restrict__ bc)
{
    const int s = blockIdx.y;
    const int* key; const int* pay;
    switch (s) {
      case 0: key = cc_dst; pay = cc_src; break;
      case 1: key = cn_dst; pay = cn_src; break;
      default: key = nn_dst; pay = nn_src; break;
    }
    __shared__ uint2 rec[CHUNK];
    __shared__ int lhist[BK], lofs[BK], lcur[BK], gbase[BK];
    __shared__ int ls[256];
    const int tid = threadIdx.x;
    const int base = blockIdx.x * CHUNK;

    int k[16], p[16];
    #pragma unroll
    for (int j = 0; j < 16; ++j) {
        int e = base + j * 256 + tid;
        bool valid = (e < NE);
        k[j] = valid ? key[e] : -1;
        p[j] = valid ? pay[e] : 0;
    }
    if (tid < BK) lhist[tid] = 0;
    __syncthreads();
    #pragma unroll
    for (int j = 0; j < 16; ++j)
        if (k[j] >= 0) atomicAdd(&lhist[k[j] >> BSHIFT], 1);
    __syncthreads();
    int v = (tid < BK) ? lhist[tid] : 0;
    ls[tid] = v;
    __syncthreads();
    #pragma unroll
    for (int off = 1; off < 128; off <<= 1) {
        int t = (tid >= off) ? ls[tid - off] : 0;
        __syncthreads();
        ls[tid] += t;
        __syncthreads();
    }
    if (tid < BK) { int e = ls[tid] - v; lofs[tid] = e; lcur[tid] = e; }
    __syncthreads();
    #pragma unroll
    for (int j = 0; j < 16; ++j) {
        if (k[j] >= 0) {
            int b = k[j] >> BSHIFT;
            int pos = atomicAdd(&lcur[b], 1);
            rec[pos] = make_uint2((unsigned)k[j], (unsigned)p[j]);
        }
    }
    __syncthreads();
    if (tid < BK) {
        int c = lcur[tid] - lofs[tid];
        gbase[tid] = (c > 0) ? atomicAdd(&bc[s * BK + tid], c) : 0;
    }
    __syncthreads();
    int total = ls[127];
    for (int i = tid; i < total; i += 256) {
        uint2 r = rec[i];
        int b = (int)(r.x >> BSHIFT);
        int gi = gbase[b] + (i - lofs[b]);
        R[((size_t)s * NBUCK + b) * CAP + gi] = r;
    }
}

// ---------------------------------------------------------------------------
// Phase B: one block per (bucket, stream): rowptr + dense col fill.
// ---------------------------------------------------------------------------
__global__ __launch_bounds__(256) void binB_k(
    const uint2* __restrict__ R, const int* __restrict__ bc,
    int* __restrict__ rp3, int* __restrict__ col3)
{
    const int b = blockIdx.x;
    const int s = blockIdx.y;
    const int tid = threadIdx.x;
    __shared__ int cnt[512];
    __shared__ int lofs[512];
    __shared__ int ls[256];
    __shared__ int sbase;

    const int nrec = bc[s * BK + b];
    const uint2* rec = R + ((size_t)s * NBUCK + b) * CAP;

    for (int i = tid; i < 512; i += 256) cnt[i] = 0;
    __syncthreads();
    for (int i = tid; i < nrec; i += 256)
        atomicAdd(&cnt[rec[i].x & 511], 1);
    __syncthreads();

    {
        int v = (tid < b) ? bc[s * BK + tid] : 0;
        ls[tid] = v;
        __syncthreads();
        for (int off = 128; off > 0; off >>= 1) {
            if (tid < off) ls[tid] += ls[tid + off];
            __syncthreads();
        }
        if (tid == 0) sbase = ls[0];
        __syncthreads();
    }
    const int colBase = sbase;

    int v0 = cnt[2 * tid], v1 = cnt[2 * tid + 1];
    int pairSum = v0 + v1;
    ls[tid] = pairSum;
    __syncthreads();
    #pragma unroll
    for (int off = 1; off < 256; off <<= 1) {
        int t = (tid >= off) ? ls[tid - off] : 0;
        __syncthreads();
        ls[tid] += t;
        __syncthreads();
    }
    int excl = ls[tid] - pairSum;
    lofs[2 * tid] = excl;
    lofs[2 * tid + 1] = excl + v0;
    __syncthreads();
    const int total = ls[255];

    int* rp = rp3 + (size_t)s * (NCN + 1);
    for (int j = tid; j < 512; j += 256) {
        int d = b * 512 + j;
        if (d < NCN) rp[d] = colBase + lofs[j];
    }
    if (b == NBUCK - 1 && tid == 0) rp[NCN] = colBase + total;
    __syncthreads();

    int* col = col3 + (size_t)s * NE + colBase;
    for (int i = tid; i < nrec; i += 256) {
        uint2 r = rec[i];
        int pos = atomicAdd(&lofs[r.x & 511], 1);
        col[pos] = (int)r.y;
    }
}

// ---------------------------------------------------------------------------
// W preconvert: fp32 W[128][128] -> bf16 hi/lo image per 64-k chunk,
// transposed with the XOR swizzle baked in (read-side XOR cancels it).
// Per matrix: chunk c in {0,1}: hi at [c*16384, +8192), lo at +8192.
// img[c][n*64+jj] = comp( W[c*64 + (jj ^ ((n&7)<<3))][n] )
// ---------------------------------------------------------------------------
__global__ __launch_bounds__(256) void wconv_k(
    const float* __restrict__ Wm0, const float* __restrict__ Wm1,
    const float* __restrict__ Wm2, const float* __restrict__ Wm3,
    const float* __restrict__ Wm4, const float* __restrict__ Wm5,
    const float* __restrict__ Wm6, const float* __restrict__ Wm7,
    ushort* __restrict__ out)
{
    const float* Ws[8] = {Wm0, Wm1, Wm2, Wm3, Wm4, Wm5, Wm6, Wm7};
    const float* W = Ws[blockIdx.x];
    ushort* o = out + (size_t)blockIdx.x * 32768;
    for (int i = threadIdx.x; i < 16384; i += 256) {
        int c = i >> 13;
        int r = i & 8191;
        int n = r >> 6;
        int jj = r & 63;
        int kk = c * 64 + (jj ^ ((n & 7) << 3));
        float wv = W[kk * 128 + n];
        ushort h = f2bf(wv);
        float lv = wv - bf2f(h);
        o[c * 16384 + r] = h;
        o[c * 16384 + 8192 + r] = f2bf(lv);
    }
}

// ---------------------------------------------------------------------------
// Generic pull aggregation, up to 3 independent streams per dispatch
// (blockIdx.y). sc == null -> SAGE mean (1/deg); else GraphConv.
// TWO rows per wave: each 32-lane half owns one row, float4 payload loads;
// col/scale loaded once per 32 edges and broadcast via __shfl(width=32).
// ---------------------------------------------------------------------------
__global__ __launch_bounds__(256) void agg_k(
    const float* __restrict__ X0, const int* __restrict__ rp0,
    const int* __restrict__ col0, const float* __restrict__ sc0,
    ushort* __restrict__ out0,
    const float* __restrict__ X1, const int* __restrict__ rp1,
    const int* __restrict__ col1, const float* __restrict__ sc1,
    ushort* __restrict__ out1,
    const float* __restrict__ X2, const int* __restrict__ rp2,
    const int* __restrict__ col2, const float* __restrict__ sc2,
    ushort* __restrict__ out2)
{
    const float* X; const int* rp; const int* col; const float* sc; ushort* out;
    if (blockIdx.y == 0)      { X = X0; rp = rp0; col = col0; sc = sc0; out = out0; }
    else if (blockIdx.y == 1) { X = X1; rp = rp1; col = col1; sc = sc1; out = out1; }
    else                      { X = X2; rp = rp2; col = col2; sc = sc2; out = out2; }

    int wid = (blockIdx.x * 256 + threadIdx.x) >> 6;
    int half = (threadIdx.x >> 5) & 1;
    int lane4 = threadIdx.x & 31;
    int row = wid * 2 + half;
    if (row >= NCN) return;
    int e0 = rp[row], e1 = rp[row + 1];
    const bool useSc = (sc != nullptr);
    float4 a = make_float4(0.f, 0.f, 0.f, 0.f);
    int e = e0;
    while (e < e1) {
        int cnt = e1 - e; if (cnt > 32) cnt = 32;
        int myc = (lane4 < cnt) ? col[e + lane4] : 0;
        float mysc = (useSc && lane4 < cnt) ? sc[myc] : 1.0f;
        int j = 0;
        for (; j + 4 <= cnt; j += 4) {
            int s0 = __shfl(myc, j, 32),     s1 = __shfl(myc, j + 1, 32);
            int s2 = __shfl(myc, j + 2, 32), s3 = __shfl(myc, j + 3, 32);
            float c0 = __shfl(mysc, j, 32),     c1 = __shfl(mysc, j + 1, 32);
            float c2 = __shfl(mysc, j + 2, 32), c3 = __shfl(mysc, j + 3, 32);
            const float4 u0 = *(const float4*)(X + (size_t)s0 * DF + lane4 * 4);
            const float4 u1 = *(const float4*)(X + (size_t)s1 * DF + lane4 * 4);
            const float4 u2 = *(const float4*)(X + (size_t)s2 * DF + lane4 * 4);
            const float4 u3 = *(const float4*)(X + (size_t)s3 * DF + lane4 * 4);
            a.x = fmaf(u0.x, c0, a.x); a.y = fmaf(u0.y, c0, a.y);
            a.z = fmaf(u0.z, c0, a.z); a.w = fmaf(u0.w, c0, a.w);
            a.x = fmaf(u1.x, c1, a.x); a.y = fmaf(u1.y, c1, a.y);
            a.z = fmaf(u1.z, c1, a.z); a.w = fmaf(u1.w, c1, a.w);
            a.x = fmaf(u2.x, c2, a.x); a.y = fmaf(u2.y, c2, a.y);
            a.z = fmaf(u2.z, c2, a.z); a.w = fmaf(u2.w, c2, a.w);
            a.x = fmaf(u3.x, c3, a.x); a.y = fmaf(u3.y, c3, a.y);
            a.z = fmaf(u3.z, c3, a.z); a.w = fmaf(u3.w, c3, a.w);
        }
        for (; j < cnt; ++j) {
            int s0 = __shfl(myc, j, 32);
            float c0 = __shfl(mysc, j, 32);
            const float4 u0 = *(const float4*)(X + (size_t)s0 * DF + lane4 * 4);
            a.x = fmaf(u0.x, c0, a.x); a.y = fmaf(u0.y, c0, a.y);
            a.z = fmaf(u0.z, c0, a.z); a.w = fmaf(u0.w, c0, a.w);
        }
        e += cnt;
    }
    int deg = e1 - e0; if (deg < 1) deg = 1;
    float dsc = useSc ? rsqrtf((float)deg) : (1.0f / (float)deg);
    a.x *= dsc; a.y *= dsc; a.z *= dsc; a.w *= dsc;
    store_split4(out, row, lane4, a);
}

// ---------------------------------------------------------------------------
// Split-bf16 MFMA GEMM: Y[M,128] = sum_s A_s[M,128] @ W_s[128,128] (+b0+b1).
// 128x128 tile (A read ONCE per row tile), 256 thr (4 waves), 32KB LDS for
// the current W chunk. A-fragments double-buffered in registers: loadA(c+1)
// issued BEFORE compute(c) so L2/L3 latency hides under 96 MFMAs + barrier.
// 3 products hi*hi + hi*lo + lo*hi (rel err ~2^-18).
// In-place (Y aliasing fp32 A_s) safe: block reads only its own 128 rows,
// all A-loads consumed by compute before the final barrier; stores after.
// ---------------------------------------------------------------------------
template<int NSRC, bool RELU, int F32S>
__global__ __launch_bounds__(256, 3) void mgemm_k(
    const void* __restrict__ A0, const void* __restrict__ A1, const void* __restrict__ A2,
    const ushort* __restrict__ Wi0, const ushort* __restrict__ Wi1, const ushort* __restrict__ Wi2,
    const float* __restrict__ b0, const float* __restrict__ b1,
    float* __restrict__ Y, int M)
{
    constexpr int NCH = 2 * NSRC;
    __shared__ ushort Wsm[16384];   // hi [0,8192) | lo [8192,16384) ushorts
    const int tid = threadIdx.x;
    const int l = tid & 63;
    const int wv = tid >> 6;
    const int r0 = blockIdx.x * 128;

    const void*   Aarr[3] = {A0, A1, A2};
    const ushort* Warr[3] = {Wi0, Wi1, Wi2};

    int arow[2];
    #pragma unroll
    for (int rt = 0; rt < 2; ++rt) {
        int r = r0 + wv * 32 + rt * 16 + (l & 15);
        arow[rt] = (r < M) ? r : (M - 1);
    }
    const int kgrp = (l >> 4) * 8;   // element offset within a 32-k step

    facc4 acc[2][8];
    #pragma unroll
    for (int rt = 0; rt < 2; ++rt)
        #pragma unroll
        for (int ct = 0; ct < 8; ++ct)
            acc[rt][ct] = (facc4){0.f, 0.f, 0.f, 0.f};

    uint4 Wr[8];
    auto loadWr = [&](int c) {
        int s = c >> 1, chalf = c & 1;
        const uint4* wp = (const uint4*)(Warr[s] + chalf * 16384);
        #pragma unroll
        for (int i = 0; i < 8; ++i) Wr[i] = wp[i * 256 + tid];
    };

    mfrag ahA[2][2], alA[2][2], ahB[2][2], alB[2][2];   // [ks][rt] x 2 buffers
    auto loadA = [&](int c, mfrag (&ah)[2][2], mfrag (&al)[2][2]) {
        int s = c >> 1;
        int k0 = (c & 1) * 64;
        if (s == F32S) {
            const float* F = (const float*)Aarr[s];
            #pragma unroll
            for (int ks = 0; ks < 2; ++ks)
                #pragma unroll
                for (int rt = 0; rt < 2; ++rt) {
                    const float* p = F + (size_t)arow[rt] * DF + k0 + ks * 32 + kgrp;
                    float4 v0 = *(const float4*)p;
                    float4 v1 = *(const float4*)(p + 4);
                    union { mfrag m; ushort u[8]; } H, L;
                    float vv0[4] = {v0.x, v0.y, v0.z, v0.w};
                    float vv1[4] = {v1.x, v1.y, v1.z, v1.w};
                    #pragma unroll
                    for (int j = 0; j < 4; ++j) {
                        ushort h = f2bf(vv0[j]);
                        H.u[j] = h; L.u[j] = f2bf(vv0[j] - bf2f(h));
                    }
                    #pragma unroll
                    for (int j = 0; j < 4; ++j) {
                        ushort h = f2bf(vv1[j]);
                        H.u[4 + j] = h; L.u[4 + j] = f2bf(vv1[j] - bf2f(h));
                    }
                    ah[ks][rt] = H.m; al[ks][rt] = L.m;
                }
        } else {
            const ushort* T = (const ushort*)Aarr[s];
            #pragma unroll
            for (int ks = 0; ks < 2; ++ks)
                #pragma unroll
                for (int rt = 0; rt < 2; ++rt) {
                    size_t o = (size_t)arow[rt] * DF + k0 + ks * 32 + kgrp;
                    ah[ks][rt] = *(const mfrag*)(T + o);
                    al[ks][rt] = *(const mfrag*)(T + (size_t)NCN * DF + o);
                }
        }
    };

    auto compute = [&](const mfrag (&ah)[2][2], const mfrag (&al)[2][2]) {
        #pragma unroll
        for (int ks = 0; ks < 2; ++ks) {
            const int kbyte = ks * 64 + (l >> 4) * 16;
            #pragma unroll
            for (int ct = 0; ct < 8; ++ct) {
                int colc = ct * 16 + (l & 15);
                int widx = colc * 64 + ((kbyte ^ ((colc & 7) << 4)) >> 1);
                mfrag w_hi = *(const mfrag*)(Wsm + widx);
                mfrag w_lo = *(const mfrag*)(Wsm + 8192 + widx);
                #pragma unroll
                for (int rt = 0; rt < 2; ++rt) {
                    acc[rt][ct] = __builtin_amdgcn_mfma_f32_16x16x32_bf16(ah[ks][rt], w_hi, acc[rt][ct], 0, 0, 0);
                    acc[rt][ct] = __builtin_amdgcn_mfma_f32_16x16x32_bf16(ah[ks][rt], w_lo, acc[rt][ct], 0, 0, 0);
                    acc[rt][ct] = __builtin_amdgcn_mfma_f32_16x16x32_bf16(al[ks][rt], w_hi, acc[rt][ct], 0, 0, 0);
                }
            }
        }
    };

    loadWr(0);
    loadA(0, ahA, alA);
    #pragma unroll
    for (int c = 0; c < NCH; ++c) {
        __syncthreads();   // all waves done reading Wsm(prev)
        {
            uint4* wd = (uint4*)Wsm;
            #pragma unroll
            for (int i = 0; i < 8; ++i) wd[i * 256 + tid] = Wr[i];
        }
        if (c + 1 < NCH) {
            loadWr(c + 1);
            if ((c & 1) == 0) loadA(c + 1, ahB, alB);
            else              loadA(c + 1, ahA, alA);
        }
        __syncthreads();   // Wsm(c) visible
        if ((c & 1) == 0) compute(ahA, alA);
        else              compute(ahB, alB);
    }
    __syncthreads();   // all waves' A-reads retired before any in-place store

    float bias[8];
    #pragma unroll
    for (int ct = 0; ct < 8; ++ct) {
        int colc = ct * 16 + (l & 15);
        float bv = b0 ? b0[colc] : 0.f;
        if (b1) bv += b1[colc];
        bias[ct] = bv;
    }
    #pragma unroll
    for (int rt = 0; rt < 2; ++rt) {
        #pragma unroll
        for (int q = 0; q < 4; ++q) {
            int row = r0 + wv * 32 + rt * 16 + (l >> 4) * 4 + q;
            if (row < M) {
                #pragma unroll
                for (int ct = 0; ct < 8; ++ct) {
                    float v = acc[rt][ct][q] + bias[ct];
                    if (RELU) v = fmaxf(v, 0.f);
                    Y[(size_t)row * DF + ct * 16 + (l & 15)] = v;
                }
            }
        }
    }
}

// ---------------------------------------------------------------------------
extern "C" void kernel_launch(void* const* d_in, const int* in_sizes, int n_in,
                              void* d_out, int out_size, void* d_ws, size_t ws_size,
                              hipStream_t stream)
{
    (void)in_sizes; (void)n_in; (void)out_size; (void)ws_size;
    const float* feat_C   = (const float*)d_in[0];
    const float* feat_N   = (const float*)d_in[1];
    const float* W1_cc    = (const float*)d_in[2];
    const float* b1_cc    = (const float*)d_in[3];
    const float* W1_cn    = (const float*)d_in[4];
    const float* b1_cn    = (const float*)d_in[5];
    const float* W1_self  = (const float*)d_in[6];
    const float* W1_neigh = (const float*)d_in[7];
    const float* b1_nn    = (const float*)d_in[8];
    const float* W2_cc    = (const float*)d_in[9];
    const float* b2_cc    = (const float*)d_in[10];
    const float* W2_cn    = (const float*)d_in[11];
    const float* b2_cn    = (const float*)d_in[12];
    const float* W2_self  = (const float*)d_in[13];
    const float* W2_neigh = (const float*)d_in[14];
    const float* b2_nn    = (const float*)d_in[15];
    const int* cc_src = (const int*)d_in[16];
    const int* cc_dst = (const int*)d_in[17];
    const int* cn_src = (const int*)d_in[18];
    const int* cn_dst = (const int*)d_in[19];
    const int* nn_src = (const int*)d_in[20];
    const int* nn_dst = (const int*)d_in[21];

    char* ws = (char*)d_ws;
    size_t off = 0;
    auto take = [&](size_t bytes) -> char* {
        char* p = ws + off;
        off = (off + bytes + 255) & ~(size_t)255;
        return p;
    };
    int*    rp3    = (int*)take((size_t)3 * (NCN + 1) * sizeof(int));
    int*    col3   = (int*)take((size_t)3 * NE * sizeof(int));
    float*  snorm2 = (float*)take((size_t)2 * NCN * sizeof(float));
    int*    cnt2   = (int*)take((size_t)2 * NCN * sizeof(int));
    int*    bc     = (int*)take((size_t)3 * BK * sizeof(int));
    ushort* Wimg   = (ushort*)take((size_t)8 * 32768 * sizeof(ushort));  // 512KB
    // R (16.9MB, 3 streams) dead after binB; overlap with the split tables
    char* bigRegion = take((size_t)2 * 2 * NCN * DF * sizeof(ushort));   // 51.2MB
    uint2*  R  = (uint2*)bigRegion;
    ushort* P0 = (ushort*)bigRegion;
    ushort* P1 = (ushort*)(bigRegion + (size_t)2 * NCN * DF * sizeof(ushort));

    float* oC = (float*)d_out;           // also hosts hC / the nn split-table
    float* oN = oC + (size_t)NCN * DF;   // also hosts hN
    ushort* oCsplit = (ushort*)oC;       // hi | lo split table in oC region

    const int edgeBlocks = (NE + 255) / 256;
    const int binABlocks = (NE + CHUNK - 1) / CHUNK;
    const int aggBlocks  = (((NCN + 1) / 2) * 64 + 255) / 256;   // 2 rows/wave
    const int gemmBlocks = (NCN + 127) / 128;

    // mats: 0:W1_cc 1:W1_cn 2:W1_neigh 3:W1_self 4:W2_cc 5:W2_cn 6:W2_neigh 7:W2_self
    auto img = [&](int m) { return (const ushort*)(Wimg + (size_t)m * 32768); };
    const int* rpCC = rp3 + 0 * (NCN + 1);
    const int* rpCN = rp3 + 1 * (NCN + 1);
    const int* rpNN = rp3 + 2 * (NCN + 1);
    const int* colCC = col3 + 0 * NE;
    const int* colCN = col3 + 1 * NE;
    const int* colNN = col3 + 2 * NE;
    const float* snCC = snorm2 + 0 * NCN;
    const float* snCN = snorm2 + 1 * NCN;

    // ---- CSR + norms + W preconvert ----
    hipMemsetAsync(cnt2, 0, (size_t)2 * NCN * sizeof(int), stream);
    hipMemsetAsync(bc, 0, (size_t)3 * BK * sizeof(int), stream);
    hist2_k<<<edgeBlocks, 256, 0, stream>>>(cc_src, cn_src, cnt2);
    srcnorm_k<<<(2 * NCN + 255) / 256, 256, 0, stream>>>(cnt2, snorm2, 2 * NCN);
    binA_k<<<dim3(binABlocks, 3), 256, 0, stream>>>(cc_src, cc_dst, cn_src, cn_dst,
                                                    nn_src, nn_dst, R, bc);
    binB_k<<<dim3(NBUCK, 3), 256, 0, stream>>>(R, bc, rp3, col3);
    wconv_k<<<8, 256, 0, stream>>>(W1_cc, W1_cn, W1_neigh, W1_self,
                                   W2_cc, W2_cn, W2_neigh, W2_self, Wimg);

    // ---- layer 1 ----
    // all three aggs in one dispatch: cc->P0, cn->P1, nn->oC region (free)
    agg_k<<<dim3(aggBlocks, 3), 256, 0, stream>>>(
        feat_C, rpCC, colCC, snCC, P0,
        feat_C, rpCN, colCN, snCN, P1,
        feat_N, rpNN, colNN, nullptr, oCsplit);
    // hN first (consumes oCsplit), then hC (overwrites oC region)
    mgemm_k<3, true, 2><<<gemmBlocks, 256, 0, stream>>>(P1, oCsplit, feat_N,
                                                        img(1), img(2), img(3),
                                                        b1_cn, b1_nn, oN, NCN);
    mgemm_k<1, true, -1><<<gemmBlocks, 256, 0, stream>>>(P0, nullptr, nullptr,
                                                         img(0), nullptr, nullptr,
                                                         b1_cc, nullptr, oC, NCN);

    // ---- layer 2 ----
    // cc,cn gather hC (= oC) first; then nn gather hN (= oN) -> oC region
    agg_k<<<dim3(aggBlocks, 2), 256, 0, stream>>>(
        oC, rpCC, colCC, snCC, P0,
        oC, rpCN, colCN, snCN, P1,
        nullptr, nullptr, nullptr, nullptr, nullptr);
    agg_k<<<dim3(aggBlocks, 1), 256, 0, stream>>>(
        oN, rpNN, colNN, nullptr, oCsplit,
        nullptr, nullptr, nullptr, nullptr, nullptr,
        nullptr, nullptr, nullptr, nullptr, nullptr);
    // oN second layer: reads P1, oCsplit, oN(self, fp32 in-place)
    mgemm_k<3, false, 2><<<gemmBlocks, 256, 0, stream>>>(P1, oCsplit, oN,
                                                         img(5), img(6), img(7),
                                                         b2_cn, b2_nn, oN, NCN);
    mgemm_k<1, false, -1><<<gemmBlocks, 256, 0, stream>>>(P0, nullptr, nullptr,
                                                          img(4), nullptr, nullptr,
                                                          b2_cc, nullptr, oC, NCN);
}

// Round 8
// 425.718 us; speedup vs baseline: 1.0936x; 1.0936x over previous
//
#include <hip/hip_runtime.h>

#define NCN 50000   // nodes per type (N_C == N_N)
#define NE  500000  // edges per type
#define DF  128     // feature dim

// Binning parameters
#define BSHIFT 9                 // 512 dst nodes per bucket
#define NBUCK 98                 // ceil(50000/512)
#define BK 128                   // padded bucket count
#define CAP 7168                 // records per bucket (expected ~5120, uniform)
#define CHUNK 4096               // edges per binA block

typedef __attribute__((ext_vector_type(8))) short mfrag;   // 8 bf16 (4 VGPRs)
typedef __attribute__((ext_vector_type(4))) float facc4;   // 4 fp32 acc

__device__ inline ushort f2bf(float x) {                   // fp32 -> bf16 RNE
    unsigned u = __float_as_uint(x);
    unsigned r = (u + 0x7FFFu + ((u >> 16) & 1u)) >> 16;
    return (ushort)r;
}
__device__ inline float bf2f(ushort h) { return __uint_as_float(((unsigned)h) << 16); }

// split-bf16 store, float4 per 32-lane row.
// mode 0 (separated): hi at T + row*DF, lo at T + NCN*DF + row*DF
// mode 1 (interleaved): hi at T + row*256, lo at T + row*256 + 128
//   (row r occupies bytes [512r, 512r+512) — same bytes as an fp32 row)
__device__ inline void store_split4m(ushort* __restrict__ T, int row, int lane4,
                                     float4 v, int mode) {
    ushort h0 = f2bf(v.x); ushort l0 = f2bf(v.x - bf2f(h0));
    ushort h1 = f2bf(v.y); ushort l1 = f2bf(v.y - bf2f(h1));
    ushort h2 = f2bf(v.z); ushort l2 = f2bf(v.z - bf2f(h2));
    ushort h3 = f2bf(v.w); ushort l3 = f2bf(v.w - bf2f(h3));
    uint2 hp = make_uint2((uint)h0 | ((uint)h1 << 16), (uint)h2 | ((uint)h3 << 16));
    uint2 lp = make_uint2((uint)l0 | ((uint)l1 << 16), (uint)l2 | ((uint)l3 << 16));
    size_t hiOff, loOff;
    if (mode == 0) { hiOff = (size_t)row * DF; loOff = (size_t)NCN * DF + (size_t)row * DF; }
    else           { hiOff = (size_t)row * 256; loOff = hiOff + 128; }
    *(uint2*)(T + hiOff + lane4 * 4) = hp;
    *(uint2*)(T + loOff + lane4 * 4) = lp;
}

// ---------------------------------------------------------------------------
// Out-degree histograms for the two GraphConv src-norm tables (L2-resident).
// ---------------------------------------------------------------------------
__global__ __launch_bounds__(256) void hist2_k(
    const int* __restrict__ cc_src, const int* __restrict__ cn_src,
    int* __restrict__ cnt2)
{
    int i = blockIdx.x * 256 + threadIdx.x;
    if (i >= NE) return;
    atomicAdd(&cnt2[cc_src[i]], 1);
    atomicAdd(&cnt2[NCN + cn_src[i]], 1);
}

__global__ __launch_bounds__(256) void srcnorm_k(
    const int* __restrict__ cnt2, float* __restrict__ snorm2, int n2)
{
    int i = blockIdx.x * 256 + threadIdx.x;
    if (i >= n2) return;
    int c = cnt2[i]; if (c < 1) c = 1;
    snorm2[i] = rsqrtf((float)c);
}

// ---------------------------------------------------------------------------
// Phase A: block-local counting sort of CHUNK edges into NBUCK dst-buckets,
// flushed as contiguous runs. streams: 0=cc 1=cn 2=nn (dst-keyed, src payload)
// ---------------------------------------------------------------------------
__global__ __launch_bounds__(256) void binA_k(
    const int* __restrict__ cc_src, const int* __restrict__ cc_dst,
    const int* __restrict__ cn_src, const int* __restrict__ cn_dst,
    const int* __restrict__ nn_src, const int* __restrict__ nn_dst,
    uint2* __restrict__ R, int* __restrict__ bc)
{
    const int s = blockIdx.y;
    const int* key; const int* pay;
    switch (s) {
      case 0: key = cc_dst; pay = cc_src; break;
      case 1: key = cn_dst; pay = cn_src; break;
      default: key = nn_dst; pay = nn_src; break;
    }
    __shared__ uint2 rec[CHUNK];
    __shared__ int lhist[BK], lofs[BK], lcur[BK], gbase[BK];
    __shared__ int ls[256];
    const int tid = threadIdx.x;
    const int base = blockIdx.x * CHUNK;

    int k[16], p[16];
    #pragma unroll
    for (int j = 0; j < 16; ++j) {
        int e = base + j * 256 + tid;
        bool valid = (e < NE);
        k[j] = valid ? key[e] : -1;
        p[j] = valid ? pay[e] : 0;
    }
    if (tid < BK) lhist[tid] = 0;
    __syncthreads();
    #pragma unroll
    for (int j = 0; j < 16; ++j)
        if (k[j] >= 0) atomicAdd(&lhist[k[j] >> BSHIFT], 1);
    __syncthreads();
    int v = (tid < BK) ? lhist[tid] : 0;
    ls[tid] = v;
    __syncthreads();
    #pragma unroll
    for (int off = 1; off < 128; off <<= 1) {
        int t = (tid >= off) ? ls[tid - off] : 0;
        __syncthreads();
        ls[tid] += t;
        __syncthreads();
    }
    if (tid < BK) { int e = ls[tid] - v; lofs[tid] = e; lcur[tid] = e; }
    __syncthreads();
    #pragma unroll
    for (int j = 0; j < 16; ++j) {
        if (k[j] >= 0) {
            int b = k[j] >> BSHIFT;
            int pos = atomicAdd(&lcur[b], 1);
            rec[pos] = make_uint2((unsigned)k[j], (unsigned)p[j]);
        }
    }
    __syncthreads();
    if (tid < BK) {
        int c = lcur[tid] - lofs[tid];
        gbase[tid] = (c > 0) ? atomicAdd(&bc[s * BK + tid], c) : 0;
    }
    __syncthreads();
    int total = ls[127];
    for (int i = tid; i < total; i += 256) {
        uint2 r = rec[i];
        int b = (int)(r.x >> BSHIFT);
        int gi = gbase[b] + (i - lofs[b]);
        R[((size_t)s * NBUCK + b) * CAP + gi] = r;
    }
}

// ---------------------------------------------------------------------------
// Phase B: one block per (bucket, stream): rowptr + dense col fill.
// ---------------------------------------------------------------------------
__global__ __launch_bounds__(256) void binB_k(
    const uint2* __restrict__ R, const int* __restrict__ bc,
    int* __restrict__ rp3, int* __restrict__ col3)
{
    const int b = blockIdx.x;
    const int s = blockIdx.y;
    const int tid = threadIdx.x;
    __shared__ int cnt[512];
    __shared__ int lofs[512];
    __shared__ int ls[256];
    __shared__ int sbase;

    const int nrec = bc[s * BK + b];
    const uint2* rec = R + ((size_t)s * NBUCK + b) * CAP;

    for (int i = tid; i < 512; i += 256) cnt[i] = 0;
    __syncthreads();
    for (int i = tid; i < nrec; i += 256)
        atomicAdd(&cnt[rec[i].x & 511], 1);
    __syncthreads();

    {
        int v = (tid < b) ? bc[s * BK + tid] : 0;
        ls[tid] = v;
        __syncthreads();
        for (int off = 128; off > 0; off >>= 1) {
            if (tid < off) ls[tid] += ls[tid + off];
            __syncthreads();
        }
        if (tid == 0) sbase = ls[0];
        __syncthreads();
    }
    const int colBase = sbase;

    int v0 = cnt[2 * tid], v1 = cnt[2 * tid + 1];
    int pairSum = v0 + v1;
    ls[tid] = pairSum;
    __syncthreads();
    #pragma unroll
    for (int off = 1; off < 256; off <<= 1) {
        int t = (tid >= off) ? ls[tid - off] : 0;
        __syncthreads();
        ls[tid] += t;
        __syncthreads();
    }
    int excl = ls[tid] - pairSum;
    lofs[2 * tid] = excl;
    lofs[2 * tid + 1] = excl + v0;
    __syncthreads();
    const int total = ls[255];

    int* rp = rp3 + (size_t)s * (NCN + 1);
    for (int j = tid; j < 512; j += 256) {
        int d = b * 512 + j;
        if (d < NCN) rp[d] = colBase + lofs[j];
    }
    if (b == NBUCK - 1 && tid == 0) rp[NCN] = colBase + total;
    __syncthreads();

    int* col = col3 + (size_t)s * NE + colBase;
    for (int i = tid; i < nrec; i += 256) {
        uint2 r = rec[i];
        int pos = atomicAdd(&lofs[r.x & 511], 1);
        col[pos] = (int)r.y;
    }
}

// ---------------------------------------------------------------------------
// W preconvert: fp32 W[128][128] -> bf16 hi/lo image per 64-k chunk,
// transposed with the XOR swizzle baked in (read-side XOR cancels it).
// ---------------------------------------------------------------------------
__global__ __launch_bounds__(256) void wconv_k(
    const float* __restrict__ Wm0, const float* __restrict__ Wm1,
    const float* __restrict__ Wm2, const float* __restrict__ Wm3,
    const float* __restrict__ Wm4, const float* __restrict__ Wm5,
    const float* __restrict__ Wm6, const float* __restrict__ Wm7,
    ushort* __restrict__ out)
{
    const float* Ws[8] = {Wm0, Wm1, Wm2, Wm3, Wm4, Wm5, Wm6, Wm7};
    const float* W = Ws[blockIdx.x];
    ushort* o = out + (size_t)blockIdx.x * 32768;
    for (int i = threadIdx.x; i < 16384; i += 256) {
        int c = i >> 13;
        int r = i & 8191;
        int n = r >> 6;
        int jj = r & 63;
        int kk = c * 64 + (jj ^ ((n & 7) << 3));
        float wv = W[kk * 128 + n];
        ushort h = f2bf(wv);
        float lv = wv - bf2f(h);
        o[c * 16384 + r] = h;
        o[c * 16384 + 8192 + r] = f2bf(lv);
    }
}

// ---------------------------------------------------------------------------
// Generic pull aggregation, up to 3 streams per dispatch (blockIdx.y).
// sc == null -> SAGE mean; else GraphConv. Two rows per wave (32-lane
// halves), float4 payloads, shfl-broadcast col/scale. Output layout mode
// per stream (0 separated, 1 interleaved).
// ---------------------------------------------------------------------------
__global__ __launch_bounds__(256) void agg_k(
    const float* __restrict__ X0, const int* __restrict__ rp0,
    const int* __restrict__ col0, const float* __restrict__ sc0,
    ushort* __restrict__ out0, int m0,
    const float* __restrict__ X1, const int* __restrict__ rp1,
    const int* __restrict__ col1, const float* __restrict__ sc1,
    ushort* __restrict__ out1, int m1,
    const float* __restrict__ X2, const int* __restrict__ rp2,
    const int* __restrict__ col2, const float* __restrict__ sc2,
    ushort* __restrict__ out2, int m2)
{
    const float* X; const int* rp; const int* col; const float* sc; ushort* out; int mode;
    if (blockIdx.y == 0)      { X = X0; rp = rp0; col = col0; sc = sc0; out = out0; mode = m0; }
    else if (blockIdx.y == 1) { X = X1; rp = rp1; col = col1; sc = sc1; out = out1; mode = m1; }
    else                      { X = X2; rp = rp2; col = col2; sc = sc2; out = out2; mode = m2; }

    int wid = (blockIdx.x * 256 + threadIdx.x) >> 6;
    int half = (threadIdx.x >> 5) & 1;
    int lane4 = threadIdx.x & 31;
    int row = wid * 2 + half;
    if (row >= NCN) return;
    int e0 = rp[row], e1 = rp[row + 1];
    const bool useSc = (sc != nullptr);
    float4 a = make_float4(0.f, 0.f, 0.f, 0.f);
    int e = e0;
    while (e < e1) {
        int cnt = e1 - e; if (cnt > 32) cnt = 32;
        int myc = (lane4 < cnt) ? col[e + lane4] : 0;
        float mysc = (useSc && lane4 < cnt) ? sc[myc] : 1.0f;
        int j = 0;
        for (; j + 4 <= cnt; j += 4) {
            int s0 = __shfl(myc, j, 32),     s1 = __shfl(myc, j + 1, 32);
            int s2 = __shfl(myc, j + 2, 32), s3 = __shfl(myc, j + 3, 32);
            float c0 = __shfl(mysc, j, 32),     c1 = __shfl(mysc, j + 1, 32);
            float c2 = __shfl(mysc, j + 2, 32), c3 = __shfl(mysc, j + 3, 32);
            const float4 u0 = *(const float4*)(X + (size_t)s0 * DF + lane4 * 4);
            const float4 u1 = *(const float4*)(X + (size_t)s1 * DF + lane4 * 4);
            const float4 u2 = *(const float4*)(X + (size_t)s2 * DF + lane4 * 4);
            const float4 u3 = *(const float4*)(X + (size_t)s3 * DF + lane4 * 4);
            a.x = fmaf(u0.x, c0, a.x); a.y = fmaf(u0.y, c0, a.y);
            a.z = fmaf(u0.z, c0, a.z); a.w = fmaf(u0.w, c0, a.w);
            a.x = fmaf(u1.x, c1, a.x); a.y = fmaf(u1.y, c1, a.y);
            a.z = fmaf(u1.z, c1, a.z); a.w = fmaf(u1.w, c1, a.w);
            a.x = fmaf(u2.x, c2, a.x); a.y = fmaf(u2.y, c2, a.y);
            a.z = fmaf(u2.z, c2, a.z); a.w = fmaf(u2.w, c2, a.w);
            a.x = fmaf(u3.x, c3, a.x); a.y = fmaf(u3.y, c3, a.y);
            a.z = fmaf(u3.z, c3, a.z); a.w = fmaf(u3.w, c3, a.w);
        }
        for (; j < cnt; ++j) {
            int s0 = __shfl(myc, j, 32);
            float c0 = __shfl(mysc, j, 32);
            const float4 u0 = *(const float4*)(X + (size_t)s0 * DF + lane4 * 4);
            a.x = fmaf(u0.x, c0, a.x); a.y = fmaf(u0.y, c0, a.y);
            a.z = fmaf(u0.z, c0, a.z); a.w = fmaf(u0.w, c0, a.w);
        }
        e += cnt;
    }
    int deg = e1 - e0; if (deg < 1) deg = 1;
    float dsc = useSc ? rsqrtf((float)deg) : (1.0f / (float)deg);
    a.x *= dsc; a.y *= dsc; a.z *= dsc; a.w *= dsc;
    store_split4m(out, row, lane4, a, mode);
}

// ---------------------------------------------------------------------------
// Split-bf16 MFMA GEMM body: Y[M,128] = sum_s A_s[M,128] @ W_s (+b0+b1).
// 128x128 tile, 4 waves, 32KB LDS W chunk, SINGLE-buffered A fragments
// (VGPR live set ~150: acc 64 + A 32 + Wr 32 + addr — no spill at 3 blk/CU).
// A1INT: A1 is a per-row interleaved split table (hi|lo within row*512B) —
// used for tables living inside the output region (block-private in-place).
// 3 MFMA products hi*hi + hi*lo + lo*hi (rel err ~2^-18).
// ---------------------------------------------------------------------------
template<int NSRC, bool RELU, int F32S, bool A1INT>
__device__ __forceinline__ void gemm_body(
    ushort* __restrict__ Wsm,
    const void* __restrict__ A0, const void* __restrict__ A1, const void* __restrict__ A2,
    const ushort* __restrict__ Wi0, const ushort* __restrict__ Wi1, const ushort* __restrict__ Wi2,
    const float* __restrict__ b0, const float* __restrict__ b1,
    float* __restrict__ Y)
{
    constexpr int NCH = 2 * NSRC;
    const int tid = threadIdx.x;
    const int l = tid & 63;
    const int wv = tid >> 6;
    const int r0 = blockIdx.x * 128;
    const int M = NCN;

    const void*   Aarr[3] = {A0, A1, A2};
    const ushort* Warr[3] = {Wi0, Wi1, Wi2};

    int arow[2];
    #pragma unroll
    for (int rt = 0; rt < 2; ++rt) {
        int r = r0 + wv * 32 + rt * 16 + (l & 15);
        arow[rt] = (r < M) ? r : (M - 1);
    }
    const int kgrp = (l >> 4) * 8;   // element offset within a 32-k step

    facc4 acc[2][8];
    #pragma unroll
    for (int rt = 0; rt < 2; ++rt)
        #pragma unroll
        for (int ct = 0; ct < 8; ++ct)
            acc[rt][ct] = (facc4){0.f, 0.f, 0.f, 0.f};

    uint4 Wr[8];
    auto loadWr = [&](int c) {
        int s = c >> 1, chalf = c & 1;
        const uint4* wp = (const uint4*)(Warr[s] + chalf * 16384);
        #pragma unroll
        for (int i = 0; i < 8; ++i) Wr[i] = wp[i * 256 + tid];
    };

    mfrag ah[2][2], al[2][2];   // [ks][rt], single-buffered
    auto loadA = [&](int c) {
        int s = c >> 1;
        int k0 = (c & 1) * 64;
        if (s == F32S) {
            const float* F = (const float*)Aarr[s];
            #pragma unroll
            for (int ks = 0; ks < 2; ++ks)
                #pragma unroll
                for (int rt = 0; rt < 2; ++rt) {
                    const float* p = F + (size_t)arow[rt] * DF + k0 + ks * 32 + kgrp;
                    float4 v0 = *(const float4*)p;
                    float4 v1 = *(const float4*)(p + 4);
                    union { mfrag m; ushort u[8]; } H, L;
                    float vv0[4] = {v0.x, v0.y, v0.z, v0.w};
                    float vv1[4] = {v1.x, v1.y, v1.z, v1.w};
                    #pragma unroll
                    for (int j = 0; j < 4; ++j) {
                        ushort h = f2bf(vv0[j]);
                        H.u[j] = h; L.u[j] = f2bf(vv0[j] - bf2f(h));
                    }
                    #pragma unroll
                    for (int j = 0; j < 4; ++j) {
                        ushort h = f2bf(vv1[j]);
                        H.u[4 + j] = h; L.u[4 + j] = f2bf(vv1[j] - bf2f(h));
                    }
                    ah[ks][rt] = H.m; al[ks][rt] = L.m;
                }
        } else {
            const ushort* T = (const ushort*)Aarr[s];
            const bool INT = (s == 1 && A1INT);
            const int rs = INT ? 256 : DF;                    // ushort row stride
            const size_t lo = INT ? 128 : (size_t)NCN * DF;   // hi->lo delta
            #pragma unroll
            for (int ks = 0; ks < 2; ++ks)
                #pragma unroll
                for (int rt = 0; rt < 2; ++rt) {
                    size_t o = (size_t)arow[rt] * rs + k0 + ks * 32 + kgrp;
                    ah[ks][rt] = *(const mfrag*)(T + o);
                    al[ks][rt] = *(const mfrag*)(T + o + lo);
                }
        }
    };

    loadWr(0);
    #pragma unroll
    for (int c = 0; c < NCH; ++c) {
        __syncthreads();   // all waves done reading Wsm(prev)
        {
            uint4* wd = (uint4*)Wsm;
            #pragma unroll
            for (int i = 0; i < 8; ++i) wd[i * 256 + tid] = Wr[i];
        }
        loadA(c);                        // A latency covered by barrier + co-resident blocks
        if (c + 1 < NCH) loadWr(c + 1);  // W latency covered by compute(c)
        __syncthreads();   // Wsm(c) visible
        #pragma unroll
        for (int ks = 0; ks < 2; ++ks) {
            const int kbyte = ks * 64 + (l >> 4) * 16;
            #pragma unroll
            for (int ct = 0; ct < 8; ++ct) {
                int colc = ct * 16 + (l & 15);
                int widx = colc * 64 + ((kbyte ^ ((colc & 7) << 4)) >> 1);
                mfrag w_hi = *(const mfrag*)(Wsm + widx);
                mfrag w_lo = *(const mfrag*)(Wsm + 8192 + widx);
                #pragma unroll
                for (int rt = 0; rt < 2; ++rt) {
                    acc[rt][ct] = __builtin_amdgcn_mfma_f32_16x16x32_bf16(ah[ks][rt], w_hi, acc[rt][ct], 0, 0, 0);
                    acc[rt][ct] = __builtin_amdgcn_mfma_f32_16x16x32_bf16(ah[ks][rt], w_lo, acc[rt][ct], 0, 0, 0);
                    acc[rt][ct] = __builtin_amdgcn_mfma_f32_16x16x32_bf16(al[ks][rt], w_hi, acc[rt][ct], 0, 0, 0);
                }
            }
        }
    }
    __syncthreads();   // all waves' A-reads retired before any in-place store

    float bias[8];
    #pragma unroll
    for (int ct = 0; ct < 8; ++ct) {
        int colc = ct * 16 + (l & 15);
        float bv = b0 ? b0[colc] : 0.f;
        if (b1) bv += b1[colc];
        bias[ct] = bv;
    }
    #pragma unroll
    for (int rt = 0; rt < 2; ++rt) {
        #pragma unroll
        for (int q = 0; q < 4; ++q) {
            int row = r0 + wv * 32 + rt * 16 + (l >> 4) * 4 + q;
            if (row < M) {
                #pragma unroll
                for (int ct = 0; ct < 8; ++ct) {
                    float v = acc[rt][ct][q] + bias[ct];
                    if (RELU) v = fmaxf(v, 0.f);
                    Y[(size_t)row * DF + ct * 16 + (l & 15)] = v;
                }
            }
        }
    }
}

// Fused layer GEMM: blockIdx.z = 0 -> 3-source N job, 1 -> 1-source C job.
template<bool RELU>
__global__ __launch_bounds__(256, 2) void fgemm2_k(
    const ushort* __restrict__ AN0, const ushort* __restrict__ AN1i,
    const float* __restrict__ AN2f,
    const ushort* __restrict__ WiN0, const ushort* __restrict__ WiN1,
    const ushort* __restrict__ WiN2,
    const float* __restrict__ bN0, const float* __restrict__ bN1,
    float* __restrict__ YN,
    const ushort* __restrict__ AC0, const ushort* __restrict__ WiC,
    const float* __restrict__ bC, float* __restrict__ YC)
{
    __shared__ ushort Wsm[16384];
    if (blockIdx.z == 0)
        gemm_body<3, RELU, 2, true>(Wsm, AN0, AN1i, AN2f, WiN0, WiN1, WiN2,
                                    bN0, bN1, YN);
    else
        gemm_body<1, RELU, -1, false>(Wsm, AC0, nullptr, nullptr,
                                      WiC, nullptr, nullptr, bC, nullptr, YC);
}

// Standalone jobs for layer 2 (sequential: N reads a table in oC region,
// C then overwrites oC).
template<bool RELU>
__global__ __launch_bounds__(256, 2) void gemmN_k(
    const ushort* __restrict__ A0, const ushort* __restrict__ A1i,
    const float* __restrict__ A2f,
    const ushort* __restrict__ Wi0, const ushort* __restrict__ Wi1,
    const ushort* __restrict__ Wi2,
    const float* __restrict__ b0, const float* __restrict__ b1,
    float* __restrict__ Y)
{
    __shared__ ushort Wsm[16384];
    gemm_body<3, RELU, 2, true>(Wsm, A0, A1i, A2f, Wi0, Wi1, Wi2, b0, b1, Y);
}

template<bool RELU>
__global__ __launch_bounds__(256, 2) void gemmC_k(
    const ushort* __restrict__ A0, const ushort* __restrict__ Wi0,
    const float* __restrict__ b0, float* __restrict__ Y)
{
    __shared__ ushort Wsm[16384];
    gemm_body<1, RELU, -1, false>(Wsm, A0, nullptr, nullptr, Wi0, nullptr, nullptr,
                                  b0, nullptr, Y);
}

// ---------------------------------------------------------------------------
extern "C" void kernel_launch(void* const* d_in, const int* in_sizes, int n_in,
                              void* d_out, int out_size, void* d_ws, size_t ws_size,
                              hipStream_t stream)
{
    (void)in_sizes; (void)n_in; (void)out_size; (void)ws_size;
    const float* feat_C   = (const float*)d_in[0];
    const float* feat_N   = (const float*)d_in[1];
    const float* W1_cc    = (const float*)d_in[2];
    const float* b1_cc    = (const float*)d_in[3];
    const float* W1_cn    = (const float*)d_in[4];
    const float* b1_cn    = (const float*)d_in[5];
    const float* W1_self  = (const float*)d_in[6];
    const float* W1_neigh = (const float*)d_in[7];
    const float* b1_nn    = (const float*)d_in[8];
    const float* W2_cc    = (const float*)d_in[9];
    const float* b2_cc    = (const float*)d_in[10];
    const float* W2_cn    = (const float*)d_in[11];
    const float* b2_cn    = (const float*)d_in[12];
    const float* W2_self  = (const float*)d_in[13];
    const float* W2_neigh = (const float*)d_in[14];
    const float* b2_nn    = (const float*)d_in[15];
    const int* cc_src = (const int*)d_in[16];
    const int* cc_dst = (const int*)d_in[17];
    const int* cn_src = (const int*)d_in[18];
    const int* cn_dst = (const int*)d_in[19];
    const int* nn_src = (const int*)d_in[20];
    const int* nn_dst = (const int*)d_in[21];

    char* ws = (char*)d_ws;
    size_t off = 0;
    auto take = [&](size_t bytes) -> char* {
        char* p = ws + off;
        off = (off + bytes + 255) & ~(size_t)255;
        return p;
    };
    int*    rp3    = (int*)take((size_t)3 * (NCN + 1) * sizeof(int));
    int*    col3   = (int*)take((size_t)3 * NE * sizeof(int));
    float*  snorm2 = (float*)take((size_t)2 * NCN * sizeof(float));
    int*    cnt2   = (int*)take((size_t)2 * NCN * sizeof(int));
    int*    bc     = (int*)take((size_t)3 * BK * sizeof(int));
    ushort* Wimg   = (ushort*)take((size_t)8 * 32768 * sizeof(ushort));  // 512KB
    // R (16.9MB, 3 streams) dead after binB; overlap with the split tables
    char* bigRegion = take((size_t)2 * 2 * NCN * DF * sizeof(ushort));   // 51.2MB
    uint2*  R  = (uint2*)bigRegion;
    ushort* P0 = (ushort*)bigRegion;
    ushort* P1 = (ushort*)(bigRegion + (size_t)2 * NCN * DF * sizeof(ushort));

    float* oC = (float*)d_out;           // also hosts hC / interleaved tables
    float* oN = oC + (size_t)NCN * DF;   // also hosts hN / nn interleaved table
    ushort* oC_us = (ushort*)oC;
    ushort* oN_us = (ushort*)oN;

    const int edgeBlocks = (NE + 255) / 256;
    const int binABlocks = (NE + CHUNK - 1) / CHUNK;
    const int aggBlocks  = (((NCN + 1) / 2) * 64 + 255) / 256;   // 2 rows/wave
    const int gemmBlocks = (NCN + 127) / 128;

    // mats: 0:W1_cc 1:W1_cn 2:W1_neigh 3:W1_self 4:W2_cc 5:W2_cn 6:W2_neigh 7:W2_self
    auto img = [&](int m) { return (const ushort*)(Wimg + (size_t)m * 32768); };
    const int* rpCC = rp3 + 0 * (NCN + 1);
    const int* rpCN = rp3 + 1 * (NCN + 1);
    const int* rpNN = rp3 + 2 * (NCN + 1);
    const int* colCC = col3 + 0 * NE;
    const int* colCN = col3 + 1 * NE;
    const int* colNN = col3 + 2 * NE;
    const float* snCC = snorm2 + 0 * NCN;
    const float* snCN = snorm2 + 1 * NCN;

    // ---- CSR + norms + W preconvert ----
    hipMemsetAsync(cnt2, 0, (size_t)2 * NCN * sizeof(int), stream);
    hipMemsetAsync(bc, 0, (size_t)3 * BK * sizeof(int), stream);
    hist2_k<<<edgeBlocks, 256, 0, stream>>>(cc_src, cn_src, cnt2);
    srcnorm_k<<<(2 * NCN + 255) / 256, 256, 0, stream>>>(cnt2, snorm2, 2 * NCN);
    binA_k<<<dim3(binABlocks, 3), 256, 0, stream>>>(cc_src, cc_dst, cn_src, cn_dst,
                                                    nn_src, nn_dst, R, bc);
    binB_k<<<dim3(NBUCK, 3), 256, 0, stream>>>(R, bc, rp3, col3);
    wconv_k<<<8, 256, 0, stream>>>(W1_cc, W1_cn, W1_neigh, W1_self,
                                   W2_cc, W2_cn, W2_neigh, W2_self, Wimg);

    // ---- layer 1 ----
    // cc->P0 (sep), cn->P1 (sep), nn->oN region (interleaved; oN free)
    agg_k<<<dim3(aggBlocks, 3), 256, 0, stream>>>(
        feat_C, rpCC, colCC, snCC, P0, 0,
        feat_C, rpCN, colCN, snCN, P1, 0,
        feat_N, rpNN, colNN, nullptr, oN_us, 1);
    // fused: z=0 N job (P1, oN-int, feat_N -> oN in-place); z=1 C job (P0 -> oC)
    fgemm2_k<true><<<dim3(gemmBlocks, 1, 2), 256, 0, stream>>>(
        P1, oN_us, feat_N, img(1), img(2), img(3), b1_cn, b1_nn, oN,
        P0, img(0), b1_cc, oC);

    // ---- layer 2 ----
    // cc,cn gather hC (= oC) -> P0,P1 (sep); hC dead afterwards
    agg_k<<<dim3(aggBlocks, 2), 256, 0, stream>>>(
        oC, rpCC, colCC, snCC, P0, 0,
        oC, rpCN, colCN, snCN, P1, 0,
        nullptr, nullptr, nullptr, nullptr, nullptr, 0);
    // nn gathers hN (= oN) -> oC region (interleaved; hC dead)
    agg_k<<<dim3(aggBlocks, 1), 256, 0, stream>>>(
        oN, rpNN, colNN, nullptr, oC_us, 1,
        nullptr, nullptr, nullptr, nullptr, nullptr, 0,
        nullptr, nullptr, nullptr, nullptr, nullptr, 0);
    // N job first (reads oC-int table + oN self, writes oN in-place) ...
    gemmN_k<false><<<gemmBlocks, 256, 0, stream>>>(P1, oC_us, oN,
                                                   img(5), img(6), img(7),
                                                   b2_cn, b2_nn, oN);
    // ... then C job overwrites oC
    gemmC_k<false><<<gemmBlocks, 256, 0, stream>>>(P0, img(4), b2_cc, oC);
}